// Round 7
// baseline (39.344 us; speedup 1.0000x reference)
//
#include <hip/hip_runtime.h>
#include <math.h>
#include <stdint.h>

namespace {

constexpr int kB = 16384;
constexpr int kN = 12;
constexpr int kD = 64;
constexpr int kL = 2;
constexpr int kH = kN * kD;          // 768
constexpr float kEps = 1e-5f;

constexpr int BLOCK = 256;                    // 4 waves
constexpr int GRID  = kB / 8;                 // 2048 blocks: 2 graphs/wave, 8 waves/SIMD
constexpr int PREP_TOTAL = 4096 + 1536;       // W(4096 uints) + cls(1536 uints)
constexpr int PREP_GRID  = (PREP_TOTAL + 255) / 256;   // 22

typedef _Float16 half2v __attribute__((ext_vector_type(2)));

__device__ __forceinline__ uint32_t pack_f16(float a, float b) {
    auto p = __builtin_amdgcn_cvt_pkrtz(a, b);
    return __builtin_bit_cast(uint32_t, p);
}
__device__ __forceinline__ float fdot2(uint32_t a, uint32_t b, float c) {
    return __builtin_amdgcn_fdot2(__builtin_bit_cast(half2v, a),
                                  __builtin_bit_cast(half2v, b), c, false);
}

// x += row_ror:N of x (within the 16-lane DPP row).
template<int N>
__device__ __forceinline__ float dpp_ror_add(float x) {
    int r = __builtin_amdgcn_update_dpp(0, __builtin_bit_cast(int, x),
                                        0x120 + N, 0xF, 0xF, true);
    return x + __builtin_bit_cast(float, r);
}
// Sum over a 32-lane group; every lane of the group gets the total.
// 4 DPP row_ror (16-lane sums) + ds_swizzle xor-16 merge (proven in r5).
__device__ __forceinline__ float rowSum32(float x) {
    x = dpp_ror_add<8>(x);
    x = dpp_ror_add<4>(x);
    x = dpp_ror_add<2>(x);
    x = dpp_ror_add<1>(x);
    int sw = __builtin_amdgcn_ds_swizzle(__builtin_bit_cast(int, x), 0x401F);
    return x + __builtin_bit_cast(float, sw);
}

// tanh-GELU, 7 inst: gelu = x - x/(2^(2*log2e*y)+1), y = x(a + b x^2).
// Identical approximation to the r6 tanh form; overflow-graceful.
__device__ __forceinline__ float fast_gelu(float x) {
    const float x2 = x * x;
    const float u  = x * fmaf(x2, 0.1029440f, 2.3022081f); // 2*log2e*(0.79788456 + 0.03567741 x^2)
    const float e  = __builtin_amdgcn_exp2f(u);
    const float r  = __builtin_amdgcn_rcpf(e + 1.0f);
    return fmaf(x, -r, x);
}

// ---- prep: pack W^T and cls_w into f16-half2 tables in d_ws ----
// ws[0..4095]   : W  : idx=(l*8+dq)*256 + e*4 + j  -> h2(W[8dq+2j][e], W[8dq+2j+1][e])
//                 where W[d][e] = mp_w[l][e][d] (so the pack is 2 consecutive mp_w elems)
// ws[4096..5631]: cls: idx=4096+(n*32+sub)*4 + c  -> h2(cls_w[c][64n+2sub], ...+2sub+1)
__global__ __launch_bounds__(256)
void gnn_prep(const float* __restrict__ mp_w, const float* __restrict__ cls_w,
              uint32_t* __restrict__ ws)
{
    const int i = blockIdx.x * 256 + threadIdx.x;
    if (i < 4096) {
        const int l   = i >> 11;
        const int dq  = (i >> 8) & 7;
        const int e   = (i >> 2) & 63;
        const int j   = i & 3;
        const float2 w = *(const float2*)&mp_w[(l * kD + e) * kD + 8 * dq + 2 * j];
        ws[i] = pack_f16(w.x, w.y);
    } else if (i < PREP_TOTAL) {
        const int k   = i - 4096;
        const int c   = k & 3;
        const int sub = (k >> 2) & 31;
        const int n   = k >> 7;
        const float2 w = *(const float2*)&cls_w[c * kH + n * kD + 2 * sub];
        ws[i] = pack_f16(w.x, w.y);
    }
}

__global__ __launch_bounds__(BLOCK, 8)
void gnn_main(const float* __restrict__ x,
              const float* __restrict__ mp_b,
              const float* __restrict__ attn_w,
              const float* __restrict__ ln_g,
              const float* __restrict__ ln_b,
              const float* __restrict__ cls_b,
              const uint32_t* __restrict__ ws,
              float* __restrict__ out)
{
    __shared__ uint32_t qpu[4][2][32];   // per-wave q exchange, 1 KB total

    const int tid  = threadIdx.x;
    const int lane = tid & 63;
    const int wid  = tid >> 6;
    const int grp  = lane >> 5;          // graph slot in wave (0..1)
    const int sub  = lane & 31;          // lane in graph; owns feats 2sub, 2sub+1
    const int e0   = 2 * sub;
    const int b    = (blockIdx.x * 4 + wid) * 2 + grp;

    float2 h2[kN];
    const float* xb = x + b * kH + e0;
#pragma unroll
    for (int n = 0; n < kN; ++n)
        h2[n] = *(const float2*)(xb + n * kD);

#pragma unroll
    for (int l = 0; l < kL; ++l) {
        const float2 w2v = *(const float2*)&attn_w[l * (2 * kD) + kD + e0];

        // ---- ej -> exp -> sum & q, fused (w1 + attn_b cancel in softmax;
        //      |ej| <~ 1 since w2 scale 0.02 and h LN-normalized: no max-sub)
        float sumA = 0.f, sumB = 0.f;
        float2 qA = make_float2(0.f, 0.f), qB = make_float2(0.f, 0.f);
#pragma unroll
        for (int n = 0; n < kN; ++n) {
            float v = fmaf(h2[n].y, w2v.y, h2[n].x * w2v.x);
            v = rowSum32(v);
            const float sn = __expf(v);
            if (n & 1) {
                sumB += sn;
                qB.x = fmaf(sn, h2[n].x, qB.x);
                qB.y = fmaf(sn, h2[n].y, qB.y);
            } else {
                sumA += sn;
                qA.x = fmaf(sn, h2[n].x, qA.x);
                qA.y = fmaf(sn, h2[n].y, qA.y);
            }
        }
        const float inv = __builtin_amdgcn_rcpf(sumA + sumB);

        qpu[wid][grp][sub] = pack_f16(qA.x + qB.x, qA.y + qB.y);
        __builtin_amdgcn_wave_barrier();   // same-wave LDS RAW: ordered by lgkmcnt

        // ---- agg[e] = inv * sum_d q[d] W[d][e] + mp_b[e]; lane owns e0, e0+1
        float c0 = 0.f, c1 = 0.f;
        const uint32_t* Wl   = ws + l * 2048;
        const uint32_t* qrow = &qpu[wid][grp][0];
#pragma unroll
        for (int dq = 0; dq < 8; ++dq) {
            const uint4 qv = *(const uint4*)&qrow[4 * dq];          // q[8dq..8dq+7]
            const uint4 w0 = *(const uint4*)&Wl[dq * 256 + e0 * 4];      // e0
            const uint4 w1 = *(const uint4*)&Wl[dq * 256 + e0 * 4 + 4];  // e0+1
            c0 = fdot2(qv.x, w0.x, c0); c0 = fdot2(qv.y, w0.y, c0);
            c0 = fdot2(qv.z, w0.z, c0); c0 = fdot2(qv.w, w0.w, c0);
            c1 = fdot2(qv.x, w1.x, c1); c1 = fdot2(qv.y, w1.y, c1);
            c1 = fdot2(qv.z, w1.z, c1); c1 = fdot2(qv.w, w1.w, c1);
        }
        const float2 mb2 = *(const float2*)&mp_b[l * kD + e0];
        const float ccx = fmaf(c0, inv, mb2.x);
        const float ccy = fmaf(c1, inv, mb2.y);

        // ---- residual + GELU + LayerNorm ----
        const float2 g2 = *(const float2*)&ln_g[l * kD + e0];
        const float2 b2 = *(const float2*)&ln_b[l * kD + e0];
#pragma unroll
        for (int n = 0; n < kN; ++n) {
            const float ge0 = fast_gelu(h2[n].x + ccx);
            const float ge1 = fast_gelu(h2[n].y + ccy);
            float s1 = ge0 + ge1;
            float s2 = fmaf(ge0, ge0, ge1 * ge1);
            s1 = rowSum32(s1);
            s2 = rowSum32(s2);
            const float mu  = s1 * (1.f / 64.f);
            const float var = fmaf(s2, 1.f / 64.f, -mu * mu);
            const float rs  = __builtin_amdgcn_rsqf(var + kEps);
            h2[n].x = fmaf(ge0 - mu, rs * g2.x, b2.x);
            h2[n].y = fmaf(ge1 - mu, rs * g2.y, b2.y);
        }
    }

    // ---- classifier (f16-packed cls_w from ws) ----
    float p0 = 0.f, p1 = 0.f, p2 = 0.f, p3 = 0.f;
#pragma unroll
    for (int n = 0; n < kN; ++n) {
        const uint32_t hp = pack_f16(h2[n].x, h2[n].y);
        const uint4 cv = *(const uint4*)&ws[4096 + (n * 32 + sub) * 4];
        p0 = fdot2(hp, cv.x, p0);
        p1 = fdot2(hp, cv.y, p1);
        p2 = fdot2(hp, cv.z, p2);
        p3 = fdot2(hp, cv.w, p3);
    }
    p0 = rowSum32(p0);
    p1 = rowSum32(p1);
    p2 = rowSum32(p2);
    p3 = rowSum32(p3);

    if (sub == 0) {
        const float4 cb = *(const float4*)cls_b;
        *(float4*)&out[b * 4] = make_float4(p0 + cb.x, p1 + cb.y,
                                            p2 + cb.z, p3 + cb.w);
    }
}

} // namespace

extern "C" void kernel_launch(void* const* d_in, const int* in_sizes, int n_in,
                              void* d_out, int out_size, void* d_ws, size_t ws_size,
                              hipStream_t stream)
{
    const float* x      = (const float*)d_in[0];
    const float* mp_w   = (const float*)d_in[1];
    const float* mp_b   = (const float*)d_in[2];
    const float* attn_w = (const float*)d_in[3];
    // d_in[4] = attn_b : cancels in softmax, unused
    const float* ln_g   = (const float*)d_in[5];
    const float* ln_b   = (const float*)d_in[6];
    const float* cls_w  = (const float*)d_in[7];
    const float* cls_b  = (const float*)d_in[8];
    float* out = (float*)d_out;
    uint32_t* ws = (uint32_t*)d_ws;

    gnn_prep<<<PREP_GRID, 256, 0, stream>>>(mp_w, cls_w, ws);
    gnn_main<<<GRID, BLOCK, 0, stream>>>(x, mp_b, attn_w, ln_g, ln_b,
                                         cls_b, ws, out);
}